// Round 5
// baseline (864.505 us; speedup 1.0000x reference)
//
#include <hip/hip_runtime.h>
#include <hip/hip_bf16.h>
#include <stdint.h>

typedef __hip_bfloat16 bf16;
typedef __attribute__((ext_vector_type(8))) short short8;
typedef __attribute__((ext_vector_type(4))) float f32x4;
typedef __attribute__((ext_vector_type(8))) int i32x8;

#define BM 128
#define BN 128

__device__ __forceinline__ unsigned short f2bf_bits(float x) {
    return __builtin_bit_cast(unsigned short, __float2bfloat16(x));
}

__device__ __forceinline__ float bfbits2f(unsigned short b) {
    return __builtin_bit_cast(float, (unsigned)b << 16);
}

// async global->LDS, 16B per lane, LDS dest = wave-uniform base + lane*16
__device__ __forceinline__ void gload_lds16(const void* g, void* l) {
    __builtin_amdgcn_global_load_lds(
        (const __attribute__((address_space(1))) void*)g,
        (__attribute__((address_space(3))) void*)l,
        16, 0, 0);
}

__device__ __forceinline__ i32x8 ldfrag32(const uint8_t* p) {
    int4 a = *reinterpret_cast<const int4*>(p);
    int4 b = *reinterpret_cast<const int4*>(p + 16);
    i32x8 r;
    r[0] = a.x; r[1] = a.y; r[2] = a.z; r[3] = a.w;
    r[4] = b.x; r[5] = b.y; r[6] = b.z; r[7] = b.w;
    return r;
}

__global__ void cvt_f32_bf16_x4(const float* __restrict__ in, unsigned short* __restrict__ out, int n4) {
    int i = blockIdx.x * 256 + threadIdx.x;
    if (i < n4) {
        float4 v = reinterpret_cast<const float4*>(in)[i];
        ushort4 o;
        o.x = f2bf_bits(v.x); o.y = f2bf_bits(v.y);
        o.z = f2bf_bits(v.z); o.w = f2bf_bits(v.w);
        reinterpret_cast<ushort4*>(out)[i] = o;
    }
}

// W[z] fp32 [1024][1024] -> Wt bf16 [z][n][k] (transposed)
__global__ void wtrans_kernel(const float* __restrict__ W0, const float* __restrict__ W1,
                              const float* __restrict__ W2, bf16* __restrict__ Wt) {
    __shared__ float tile[32][33];
    const int z = blockIdx.z;
    const float* in = (z == 0) ? W0 : (z == 1) ? W1 : W2;
    bf16* out = Wt + (size_t)z * 1024 * 1024;
    const int bx = blockIdx.x, by = blockIdx.y, tx = threadIdx.x;
    for (int r = threadIdx.y; r < 32; r += 8)
        tile[r][tx] = in[(size_t)(by * 32 + r) * 1024 + bx * 32 + tx];
    __syncthreads();
    for (int r = threadIdx.y; r < 32; r += 8)
        out[(size_t)(bx * 32 + r) * 1024 + by * 32 + tx] = __float2bfloat16(tile[tx][r]);
}

// bf16 transpose: in [rows][cols] -> out [cols][rows]
__global__ void tpose_bf16(const bf16* __restrict__ in, bf16* __restrict__ out, int rows, int cols) {
    __shared__ bf16 tile[32][33];
    const int bx = blockIdx.x, by = blockIdx.y, tx = threadIdx.x;
    for (int r = threadIdx.y; r < 32; r += 8)
        tile[r][tx] = in[(size_t)(by * 32 + r) * cols + bx * 32 + tx];
    __syncthreads();
    for (int r = threadIdx.y; r < 32; r += 8)
        out[(size_t)(bx * 32 + r) * rows + by * 32 + tx] = tile[tx][r];
}

__global__ void scale_rows(float* __restrict__ out, const float* __restrict__ lsum) {
    int i = blockIdx.x * 256 + threadIdx.x;
    float4 v = reinterpret_cast<float4*>(out)[i];
    float inv = 1.0f / lsum[i >> 8];
    v.x *= inv; v.y *= inv; v.z *= inv; v.w *= inv;
    reinterpret_cast<float4*>(out)[i] = v;
}

// ---------------- bf16 GEMM (QKV / O) ----------------
// C[M][N] = A[M][K] * B[N][K]^T, KH stacked [128][32] bf16 half-tiles.
// MODE 0: QKV — z<2: store fp8 e4m3 into qk8 slab z; z==2: store bf16 into outb (v)
// MODE 2: outf += C                (chunked O fallback)
// MODE 3: outf  = C / lsum[row]    (full-P O path)
template <int MODE, int KH>
__global__ __launch_bounds__(256, 2)
void gemm_bt(const bf16* __restrict__ A, const bf16* __restrict__ B,
             const float* __restrict__ b0, const float* __restrict__ b1,
             const float* __restrict__ b2, float* __restrict__ lsum,
             bf16* __restrict__ outb, float* __restrict__ outf,
             uint8_t* __restrict__ qk8,
             int M, int N, int K, int ldb, int ldout, float scale) {
    constexpr int TILE = 128 * 32;
    constexpr int SELEMS = (2 * KH * TILE < 9216) ? 9216 : 2 * KH * TILE;
    __shared__ bf16 smem[SELEMS];
    bf16* As = smem;
    bf16* Bs = smem + KH * TILE;

    const int tid  = threadIdx.x;
    const int lane = tid & 63;
    const int wave = tid >> 6;
    const int wm = wave & 1, wn = wave >> 1;
    const int l16  = lane & 15;
    const int quad = lane >> 4;
    const long bm0 = (long)blockIdx.x * BM;
    const long bn0 = (long)blockIdx.y * BN;

    const float* bias = nullptr;
    int z = 0;
    if (MODE == 0) {
        z = blockIdx.z;
        B   += (size_t)z * N * K;
        bias = (z == 0) ? b0 : (z == 1) ? b1 : b2;
    }

    const int lrow = lane >> 2;
    const int lcol = (lane & 3) * 8;
    const bf16* gA[2][KH];
    const bf16* gB[2][KH];
    bf16* lA[2][KH];
    bf16* lB[2][KH];
#pragma unroll
    for (int u = 0; u < 2; u++)
#pragma unroll
        for (int h = 0; h < KH; h++) {
            gA[u][h] = A + (size_t)(bm0 + wave * 32 + u * 16 + lrow) * K + h * 32 + lcol;
            gB[u][h] = B + (size_t)(bn0 + wave * 32 + u * 16 + lrow) * ldb + h * 32 + lcol;
            lA[u][h] = As + h * TILE + (wave * 32 + u * 16) * 32;
            lB[u][h] = Bs + h * TILE + (wave * 32 + u * 16) * 32;
        }

    const bf16* Ard = As + (wm * 64 + l16) * 32 + quad * 8;
    const bf16* Brd = Bs + (wn * 64 + l16) * 32 + quad * 8;

    f32x4 acc[4][4];
    const f32x4 zero = {0.f, 0.f, 0.f, 0.f};
#pragma unroll
    for (int i = 0; i < 4; i++)
#pragma unroll
        for (int j = 0; j < 4; j++) acc[i][j] = zero;

    for (int k0 = 0; k0 < K; k0 += KH * 32) {
        __syncthreads();
#pragma unroll
        for (int u = 0; u < 2; u++)
#pragma unroll
            for (int h = 0; h < KH; h++) {
                gload_lds16(gA[u][h] + k0, lA[u][h]);
                gload_lds16(gB[u][h] + k0, lB[u][h]);
            }
        __syncthreads();
#pragma unroll
        for (int h = 0; h < KH; h++) {
            short8 af[4], bfr[4];
#pragma unroll
            for (int mi = 0; mi < 4; mi++)
                af[mi] = *reinterpret_cast<const short8*>(Ard + h * TILE + mi * 16 * 32);
#pragma unroll
            for (int ni = 0; ni < 4; ni++)
                bfr[ni] = *reinterpret_cast<const short8*>(Brd + h * TILE + ni * 16 * 32);
#pragma unroll
            for (int mi = 0; mi < 4; mi++)
#pragma unroll
                for (int ni = 0; ni < 4; ni++)
                    acc[mi][ni] = __builtin_amdgcn_mfma_f32_16x16x32_bf16(af[mi], bfr[ni], acc[mi][ni], 0, 0, 0);
        }
    }

    // C/D layout (m89/m91): col = lane&15, row = quad*4 + r
    if (MODE == 0) {
        __syncthreads();
        bf16* eb = smem + wave * 1152;  // 16 rows x stride-72 (144B, 16B-aligned)
        float bcol[4];
#pragma unroll
        for (int ni = 0; ni < 4; ni++) bcol[ni] = bias[bn0 + wn * 64 + l16 + ni * 16];
#pragma unroll
        for (int mi = 0; mi < 4; mi++) {
#pragma unroll
            for (int r = 0; r < 4; r++)
#pragma unroll
                for (int ni = 0; ni < 4; ni++)
                    eb[(quad * 4 + r) * 72 + ni * 16 + l16] =
                        __float2bfloat16(acc[mi][ni][r] + bcol[ni]);
            asm volatile("s_waitcnt lgkmcnt(0)" ::: "memory");
#pragma unroll
            for (int p = 0; p < 2; p++) {
                int r2 = p * 8 + (lane >> 3);
                int c2 = (lane & 7) * 8;
                short8 val = *reinterpret_cast<const short8*>(eb + r2 * 72 + c2);
                long row = bm0 + wm * 64 + mi * 16 + r2;
                long col = bn0 + wn * 64 + c2;
                if (z < 2) {
                    unsigned lo = 0, hi = 0;
                    lo = __builtin_amdgcn_cvt_pk_fp8_f32(bfbits2f((unsigned short)val[0]),
                                                         bfbits2f((unsigned short)val[1]), lo, false);
                    lo = __builtin_amdgcn_cvt_pk_fp8_f32(bfbits2f((unsigned short)val[2]),
                                                         bfbits2f((unsigned short)val[3]), lo, true);
                    hi = __builtin_amdgcn_cvt_pk_fp8_f32(bfbits2f((unsigned short)val[4]),
                                                         bfbits2f((unsigned short)val[5]), hi, false);
                    hi = __builtin_amdgcn_cvt_pk_fp8_f32(bfbits2f((unsigned short)val[6]),
                                                         bfbits2f((unsigned short)val[7]), hi, true);
                    int2 o; o.x = (int)lo; o.y = (int)hi;
                    *reinterpret_cast<int2*>(qk8 + (size_t)z * M * ldout + row * ldout + col) = o;
                } else {
                    *reinterpret_cast<short8*>(outb + row * (size_t)ldout + col) = val;
                }
            }
            asm volatile("s_waitcnt lgkmcnt(0)" ::: "memory");
        }
    } else {
        const int rb2 = wm * 64 + quad * 4;
        const int cb2 = wn * 64 + l16;
#pragma unroll
        for (int mi = 0; mi < 4; mi++)
#pragma unroll
            for (int r = 0; r < 4; r++) {
                long row = bm0 + rb2 + mi * 16 + r;
                float mul = (MODE == 3) ? 1.0f / lsum[row] : 0.f;
#pragma unroll
                for (int ni = 0; ni < 4; ni++) {
                    long col = bn0 + cb2 + ni * 16;
                    if (MODE == 3) outf[row * ldout + col] = acc[mi][ni][r] * mul;
                    else           outf[row * ldout + col] += acc[mi][ni][r];
                }
            }
    }
}

// ---------------- fp8 MX S-GEMM ----------------
// P[M][N] = exp(scale * q8[M][1024] * k8[N][1024]^T) via mfma_scale 16x16x128,
// const E8M0 scale = 1.0 (0x7F). LDS: per operand two [128][64B] k-half tiles.
__global__ __launch_bounds__(256, 2)
void gemm_s_fp8(const uint8_t* __restrict__ A, const uint8_t* __restrict__ B,
                float* __restrict__ lsum, bf16* __restrict__ outb,
                int ldout, float scale) {
    __shared__ uint8_t smem[32768];
    uint8_t* As = smem;            // [h][128][64]
    uint8_t* Bs = smem + 16384;

    const int tid  = threadIdx.x;
    const int lane = tid & 63;
    const int wave = tid >> 6;
    const int wm = wave & 1, wn = wave >> 1;
    const int l16  = lane & 15;
    const int quad = lane >> 4;
    const long bm0 = (long)blockIdx.x * BM;
    const long bn0 = (long)blockIdx.y * BN;

    const int lrow = lane >> 2;
    const int lcol = (lane & 3) * 16;
    const uint8_t* gA[2][2];
    const uint8_t* gB[2][2];
    uint8_t* lA[2][2];
    uint8_t* lB[2][2];
#pragma unroll
    for (int u = 0; u < 2; u++)
#pragma unroll
        for (int h = 0; h < 2; h++) {
            gA[u][h] = A + (size_t)(bm0 + wave * 32 + u * 16 + lrow) * 1024 + h * 64 + lcol;
            gB[u][h] = B + (size_t)(bn0 + wave * 32 + u * 16 + lrow) * 1024 + h * 64 + lcol;
            lA[u][h] = As + h * 8192 + (wave * 32 + u * 16) * 64;
            lB[u][h] = Bs + h * 8192 + (wave * 32 + u * 16) * 64;
        }

    // fragment base: lane holds 32 k-contig bytes: k = (lane>>5)*32? No — for
    // 16x16x128: m = lane&15, k-chunk = (lane>>4)*32 (quad), split across halves.
    const uint8_t* Ard = As + (quad >> 1) * 8192 + (wm * 64 + l16) * 64 + (quad & 1) * 32;
    const uint8_t* Brd = Bs + (quad >> 1) * 8192 + (wn * 64 + l16) * 64 + (quad & 1) * 32;

    f32x4 acc[4][4];
    const f32x4 zero = {0.f, 0.f, 0.f, 0.f};
#pragma unroll
    for (int i = 0; i < 4; i++)
#pragma unroll
        for (int j = 0; j < 4; j++) acc[i][j] = zero;

    for (int k0 = 0; k0 < 1024; k0 += 128) {
        __syncthreads();
#pragma unroll
        for (int u = 0; u < 2; u++)
#pragma unroll
            for (int h = 0; h < 2; h++) {
                gload_lds16(gA[u][h] + k0, lA[u][h]);
                gload_lds16(gB[u][h] + k0, lB[u][h]);
            }
        __syncthreads();
        i32x8 af[4], bfr[4];
#pragma unroll
        for (int mi = 0; mi < 4; mi++)
            af[mi] = ldfrag32(Ard + mi * 16 * 64);
#pragma unroll
        for (int ni = 0; ni < 4; ni++)
            bfr[ni] = ldfrag32(Brd + ni * 16 * 64);
#pragma unroll
        for (int mi = 0; mi < 4; mi++)
#pragma unroll
            for (int ni = 0; ni < 4; ni++)
                acc[mi][ni] = __builtin_amdgcn_mfma_scale_f32_16x16x128_f8f6f4(
                    af[mi], bfr[ni], acc[mi][ni], 0, 0, 0, 0x7F7F7F7F, 0, 0x7F7F7F7F);
    }

    // epilogue: exp + row-sum atomics + LDS-staged coalesced bf16 stores
    __syncthreads();
    bf16* eb = reinterpret_cast<bf16*>(smem) + wave * 1152;
#pragma unroll
    for (int mi = 0; mi < 4; mi++) {
#pragma unroll
        for (int r = 0; r < 4; r++) {
            float s = 0.f;
#pragma unroll
            for (int ni = 0; ni < 4; ni++) {
                float e = __expf(acc[mi][ni][r] * scale);
                s += e;
                eb[(quad * 4 + r) * 72 + ni * 16 + l16] = __float2bfloat16(e);
            }
            s += __shfl_xor(s, 1);
            s += __shfl_xor(s, 2);
            s += __shfl_xor(s, 4);
            s += __shfl_xor(s, 8);
            if (l16 == 0) atomicAdd(&lsum[bm0 + wm * 64 + mi * 16 + quad * 4 + r], s);
        }
        asm volatile("s_waitcnt lgkmcnt(0)" ::: "memory");
#pragma unroll
        for (int p = 0; p < 2; p++) {
            int r2 = p * 8 + (lane >> 3);
            int c2 = (lane & 7) * 8;
            short8 val = *reinterpret_cast<const short8*>(eb + r2 * 72 + c2);
            *reinterpret_cast<short8*>(
                outb + (size_t)(bm0 + wm * 64 + mi * 16 + r2) * ldout + bn0 + wn * 64 + c2) = val;
        }
        asm volatile("s_waitcnt lgkmcnt(0)" ::: "memory");
    }
}

extern "C" void kernel_launch(void* const* d_in, const int* in_sizes, int n_in,
                              void* d_out, int out_size, void* d_ws, size_t ws_size,
                              hipStream_t stream) {
    const float* feat = (const float*)d_in[0];
    const float* Wq   = (const float*)d_in[1];
    const float* bqv  = (const float*)d_in[2];
    const float* Wk   = (const float*)d_in[3];
    const float* bkv  = (const float*)d_in[4];
    const float* Wv   = (const float*)d_in[5];
    const float* bvv  = (const float*)d_in[6];
    float* outp = (float*)d_out;

    const int M = 8192, D = 1024;
    char* ws = (char*)d_ws;
    size_t off = 0;
    auto carve = [&](size_t bytes) -> char* {
        char* r = ws + off;
        off += (bytes + 255) & ~(size_t)255;
        return r;
    };
    bf16* featb   = (bf16*)carve((size_t)M * D * 2);      // dead after QKV gemm
    bf16* Wbt     = (bf16*)carve((size_t)3 * D * D * 2);  // dead after QKV gemm
    uint8_t* qk8  = (uint8_t*)carve((size_t)2 * M * D);   // q | k as fp8 e4m3
    bf16* vb      = (bf16*)carve((size_t)M * D * 2);
    float* lsum   = (float*)carve((size_t)M * 4);
    bf16* vbt     = featb;  // v^T [D][M] aliases dead featb
    size_t avail = (ws_size > off) ? ws_size - off : 0;

    int C;  // key-chunk width for P
    if      (avail >= (size_t)M * M * 2)    C = M;     // full P, 128 MB
    else if (avail >= (size_t)M * 4096 * 2) C = 4096;
    else if (avail >= (size_t)M * 2048 * 2) C = 2048;
    else                                    C = 1024;
    bf16* Pc = (bf16*)carve((size_t)M * C * 2);

    // 1) feat -> bf16
    {
        int n4 = M * D / 4;
        cvt_f32_bf16_x4<<<dim3((n4 + 255) / 256), dim3(256), 0, stream>>>(feat, (unsigned short*)featb, n4);
    }
    // 2) W transpose+convert
    wtrans_kernel<<<dim3(32, 32, 3), dim3(32, 8), 0, stream>>>(Wq, Wk, Wv, Wbt);
    // 3) QKV projection: q,k -> fp8; v -> bf16
    gemm_bt<0, 1><<<dim3(M / 128, D / 128, 3), dim3(256), 0, stream>>>(
        featb, Wbt, bqv, bkv, bvv, nullptr, vb, nullptr, qk8, M, D, D, D, D, 1.0f);
    // 4) v -> v^T
    tpose_bf16<<<dim3(D / 32, M / 32), dim3(32, 8), 0, stream>>>(vb, vbt, M, D);
    // 5) row sums
    hipMemsetAsync(lsum, 0, (size_t)M * 4, stream);

    const float scale = 0.03125f;  // 1/sqrt(1024)
    const uint8_t* q8 = qk8;
    const uint8_t* k8 = qk8 + (size_t)M * D;
    if (C == M) {
        gemm_s_fp8<<<dim3(M / 128, M / 128), dim3(256), 0, stream>>>(
            q8, k8, lsum, Pc, M, scale);
        gemm_bt<3, 2><<<dim3(M / 128, D / 128), dim3(256), 0, stream>>>(
            Pc, vbt, nullptr, nullptr, nullptr, lsum, nullptr, outp, nullptr,
            M, D, M, M, D, 0.f);
    } else {
        hipMemsetAsync(outp, 0, (size_t)M * D * 4, stream);
        for (int c = 0; c < M / C; c++) {
            gemm_s_fp8<<<dim3(M / 128, C / 128), dim3(256), 0, stream>>>(
                q8, k8 + (size_t)c * C * D, lsum, Pc, C, scale);
            gemm_bt<2, 2><<<dim3(M / 128, D / 128), dim3(256), 0, stream>>>(
                Pc, vbt + (size_t)c * C, nullptr, nullptr, nullptr, nullptr, nullptr, outp, nullptr,
                M, D, C, M, D, 0.f);
        }
        scale_rows<<<dim3(M * D / 4 / 256), dim3(256), 0, stream>>>(outp, lsum);
    }
}

// Round 6
// 464.085 us; speedup vs baseline: 1.8628x; 1.8628x over previous
//
#include <hip/hip_runtime.h>
#include <hip/hip_bf16.h>
#include <stdint.h>

typedef __hip_bfloat16 bf16;
typedef __attribute__((ext_vector_type(8))) short short8;
typedef __attribute__((ext_vector_type(4))) float f32x4;

#define BM 128
#define BN 128

__device__ __forceinline__ unsigned short f2bf_bits(float x) {
    return __builtin_bit_cast(unsigned short, __float2bfloat16(x));
}

// async global->LDS, 16B per lane, LDS dest = wave-uniform base + lane*16
__device__ __forceinline__ void gload_lds16(const bf16* g, bf16* l) {
    __builtin_amdgcn_global_load_lds(
        (const __attribute__((address_space(1))) void*)(const void*)g,
        (__attribute__((address_space(3))) void*)(void*)l,
        16, 0, 0);
}

__global__ void cvt_f32_bf16_x4(const float* __restrict__ in, unsigned short* __restrict__ out, int n4) {
    int i = blockIdx.x * 256 + threadIdx.x;
    if (i < n4) {
        float4 v = reinterpret_cast<const float4*>(in)[i];
        ushort4 o;
        o.x = f2bf_bits(v.x); o.y = f2bf_bits(v.y);
        o.z = f2bf_bits(v.z); o.w = f2bf_bits(v.w);
        reinterpret_cast<ushort4*>(out)[i] = o;
    }
}

// W[z] fp32 [1024][1024] -> Wt bf16 [z][n][k] (transposed)
__global__ void wtrans_kernel(const float* __restrict__ W0, const float* __restrict__ W1,
                              const float* __restrict__ W2, bf16* __restrict__ Wt) {
    __shared__ float tile[32][33];
    const int z = blockIdx.z;
    const float* in = (z == 0) ? W0 : (z == 1) ? W1 : W2;
    bf16* out = Wt + (size_t)z * 1024 * 1024;
    const int bx = blockIdx.x, by = blockIdx.y, tx = threadIdx.x;
    for (int r = threadIdx.y; r < 32; r += 8)
        tile[r][tx] = in[(size_t)(by * 32 + r) * 1024 + bx * 32 + tx];
    __syncthreads();
    for (int r = threadIdx.y; r < 32; r += 8)
        out[(size_t)(bx * 32 + r) * 1024 + by * 32 + tx] = __float2bfloat16(tile[tx][r]);
}

// bf16 transpose: in [rows][cols] -> out [cols][rows]
__global__ void tpose_bf16(const bf16* __restrict__ in, bf16* __restrict__ out, int rows, int cols) {
    __shared__ bf16 tile[32][33];
    const int bx = blockIdx.x, by = blockIdx.y, tx = threadIdx.x;
    for (int r = threadIdx.y; r < 32; r += 8)
        tile[r][tx] = in[(size_t)(by * 32 + r) * cols + bx * 32 + tx];
    __syncthreads();
    for (int r = threadIdx.y; r < 32; r += 8)
        out[(size_t)(bx * 32 + r) * rows + by * 32 + tx] = tile[tx][r];
}

__global__ void scale_rows(float* __restrict__ out, const float* __restrict__ lsum) {
    int i = blockIdx.x * 256 + threadIdx.x;
    float4 v = reinterpret_cast<float4*>(out)[i];
    float inv = 1.0f / lsum[i >> 8];
    v.x *= inv; v.y *= inv; v.z *= inv; v.w *= inv;
    reinterpret_cast<float4*>(out)[i] = v;
}

// C[M][N] = A[M][K] * B[N][K]^T   (A row-stride = K, B row-stride = ldb)
// LDS tiles: KH stacked [128][32] half-tiles (64 B row stride, conflict-free b128).
// SWAP=1: blockIdx.x indexes N-tiles, blockIdx.y indexes M-tiles (L2 locality for
//         the P-streaming O-gemm: consecutive blocks share one A row-slab).
// MODE 0: outb = C + bias[col]  (z-slab QKV), LDS-staged coalesced bf16 stores
// MODE 1: outb = exp(C*scale), atomicAdd row-sums -> lsum, LDS-staged stores
// MODE 2: outf += C                      (chunked O fallback)
// MODE 3: outf  = C / lsum[row]          (full-P O path)
template <int MODE, int KH, int SWAP>
__global__ __launch_bounds__(256, 2)
void gemm_bt(const bf16* __restrict__ A, const bf16* __restrict__ B,
             const float* __restrict__ b0, const float* __restrict__ b1,
             const float* __restrict__ b2, float* __restrict__ lsum,
             bf16* __restrict__ outb, float* __restrict__ outf,
             int M, int N, int K, int ldb, int ldout, float scale) {
    constexpr int TILE = 128 * 32;
    constexpr int SELEMS = (2 * KH * TILE < 9216) ? 9216 : 2 * KH * TILE;
    __shared__ bf16 smem[SELEMS];
    bf16* As = smem;             // As + h*TILE
    bf16* Bs = smem + KH * TILE; // Bs + h*TILE

    const int tid  = threadIdx.x;
    const int lane = tid & 63;
    const int wave = tid >> 6;
    const int wm = wave & 1, wn = wave >> 1;
    const int l16  = lane & 15;
    const int quad = lane >> 4;
    const long bm0 = (long)(SWAP ? blockIdx.y : blockIdx.x) * BM;
    const long bn0 = (long)(SWAP ? blockIdx.x : blockIdx.y) * BN;

    const float* bias = nullptr;
    if (MODE == 0) {
        const int z = blockIdx.z;
        B    += (size_t)z * N * K;
        outb += (size_t)z * M * ldout;
        bias  = (z == 0) ? b0 : (z == 1) ? b1 : b2;
    }

    // staging: per wave rows [wave*32, wave*32+32); u = 16-row slab, h = K-half.
    const int lrow = lane >> 2;
    const int lcol = (lane & 3) * 8;
    const bf16* gA[2][KH];
    const bf16* gB[2][KH];
    bf16* lA[2][KH];
    bf16* lB[2][KH];
#pragma unroll
    for (int u = 0; u < 2; u++)
#pragma unroll
        for (int h = 0; h < KH; h++) {
            gA[u][h] = A + (size_t)(bm0 + wave * 32 + u * 16 + lrow) * K + h * 32 + lcol;
            gB[u][h] = B + (size_t)(bn0 + wave * 32 + u * 16 + lrow) * ldb + h * 32 + lcol;
            lA[u][h] = As + h * TILE + (wave * 32 + u * 16) * 32;
            lB[u][h] = Bs + h * TILE + (wave * 32 + u * 16) * 32;
        }

    const bf16* Ard = As + (wm * 64 + l16) * 32 + quad * 8;
    const bf16* Brd = Bs + (wn * 64 + l16) * 32 + quad * 8;

    f32x4 acc[4][4];
    const f32x4 zero = {0.f, 0.f, 0.f, 0.f};
#pragma unroll
    for (int i = 0; i < 4; i++)
#pragma unroll
        for (int j = 0; j < 4; j++) acc[i][j] = zero;

    for (int k0 = 0; k0 < K; k0 += KH * 32) {
        __syncthreads();
#pragma unroll
        for (int u = 0; u < 2; u++)
#pragma unroll
            for (int h = 0; h < KH; h++) {
                gload_lds16(gA[u][h] + k0, lA[u][h]);
                gload_lds16(gB[u][h] + k0, lB[u][h]);
            }
        __syncthreads();
#pragma unroll
        for (int h = 0; h < KH; h++) {
            short8 af[4], bfr[4];
#pragma unroll
            for (int mi = 0; mi < 4; mi++)
                af[mi] = *reinterpret_cast<const short8*>(Ard + h * TILE + mi * 16 * 32);
#pragma unroll
            for (int ni = 0; ni < 4; ni++)
                bfr[ni] = *reinterpret_cast<const short8*>(Brd + h * TILE + ni * 16 * 32);
#pragma unroll
            for (int mi = 0; mi < 4; mi++)
#pragma unroll
                for (int ni = 0; ni < 4; ni++)
                    acc[mi][ni] = __builtin_amdgcn_mfma_f32_16x16x32_bf16(af[mi], bfr[ni], acc[mi][ni], 0, 0, 0);
        }
    }

    // C/D layout (m89/m91): col = lane&15, row = quad*4 + r
    if (MODE == 0 || MODE == 1) {
        __syncthreads();  // tiles dead; reuse smem for epilogue staging
        bf16* eb = smem + wave * 1152;  // 16 rows x stride-72 bf16 = 2304 B / wave
        float bcol[4];
        if (MODE == 0) {
#pragma unroll
            for (int ni = 0; ni < 4; ni++) bcol[ni] = bias[bn0 + wn * 64 + l16 + ni * 16];
        }
#pragma unroll
        for (int mi = 0; mi < 4; mi++) {
#pragma unroll
            for (int r = 0; r < 4; r++) {
                float s = 0.f;
#pragma unroll
                for (int ni = 0; ni < 4; ni++) {
                    float v = acc[mi][ni][r];
                    if (MODE == 0) v += bcol[ni];
                    else { v = __expf(v * scale); s += v; }
                    eb[(quad * 4 + r) * 72 + ni * 16 + l16] = __float2bfloat16(v);
                }
                if (MODE == 1) {
                    s += __shfl_xor(s, 1);
                    s += __shfl_xor(s, 2);
                    s += __shfl_xor(s, 4);
                    s += __shfl_xor(s, 8);
                    if (l16 == 0) atomicAdd(&lsum[bm0 + wm * 64 + mi * 16 + quad * 4 + r], s);
                }
            }
            asm volatile("s_waitcnt lgkmcnt(0)" ::: "memory");
#pragma unroll
            for (int p = 0; p < 2; p++) {
                int r2 = p * 8 + (lane >> 3);
                int c2 = (lane & 7) * 8;
                short8 val = *reinterpret_cast<const short8*>(eb + r2 * 72 + c2);
                *reinterpret_cast<short8*>(
                    outb + (size_t)(bm0 + wm * 64 + mi * 16 + r2) * ldout + bn0 + wn * 64 + c2) = val;
            }
            asm volatile("s_waitcnt lgkmcnt(0)" ::: "memory");
        }
    } else {
        const int rb2 = wm * 64 + quad * 4;
        const int cb2 = wn * 64 + l16;
#pragma unroll
        for (int mi = 0; mi < 4; mi++)
#pragma unroll
            for (int r = 0; r < 4; r++) {
                long row = bm0 + rb2 + mi * 16 + r;
                float mul = (MODE == 3) ? 1.0f / lsum[row] : 0.f;
#pragma unroll
                for (int ni = 0; ni < 4; ni++) {
                    long col = bn0 + cb2 + ni * 16;
                    if (MODE == 3) outf[row * ldout + col] = acc[mi][ni][r] * mul;
                    else           outf[row * ldout + col] += acc[mi][ni][r];
                }
            }
    }
}

extern "C" void kernel_launch(void* const* d_in, const int* in_sizes, int n_in,
                              void* d_out, int out_size, void* d_ws, size_t ws_size,
                              hipStream_t stream) {
    const float* feat = (const float*)d_in[0];
    const float* Wq   = (const float*)d_in[1];
    const float* bqv  = (const float*)d_in[2];
    const float* Wk   = (const float*)d_in[3];
    const float* bkv  = (const float*)d_in[4];
    const float* Wv   = (const float*)d_in[5];
    const float* bvv  = (const float*)d_in[6];
    float* outp = (float*)d_out;

    const int M = 8192, D = 1024;
    char* ws = (char*)d_ws;
    size_t off = 0;
    auto carve = [&](size_t bytes) -> char* {
        char* r = ws + off;
        off += (bytes + 255) & ~(size_t)255;
        return r;
    };
    bf16* featb = (bf16*)carve((size_t)M * D * 2);      // dead after QKV gemm
    bf16* Wbt   = (bf16*)carve((size_t)3 * D * D * 2);  // dead after QKV gemm
    bf16* qkv   = (bf16*)carve((size_t)3 * M * D * 2);  // q | k | v slabs
    float* lsum = (float*)carve((size_t)M * 4);
    bf16* vbt   = featb;  // v^T [D][M], aliases dead featb (tpose runs after QKV)
    size_t avail = (ws_size > off) ? ws_size - off : 0;

    int C;  // key-chunk width for P
    if      (avail >= (size_t)M * M * 2)    C = M;     // full P, 128 MB
    else if (avail >= (size_t)M * 4096 * 2) C = 4096;
    else if (avail >= (size_t)M * 2048 * 2) C = 2048;
    else                                    C = 1024;
    bf16* Pc = (bf16*)carve((size_t)M * C * 2);

    // 1) feat -> bf16
    {
        int n4 = M * D / 4;
        cvt_f32_bf16_x4<<<dim3((n4 + 255) / 256), dim3(256), 0, stream>>>(feat, (unsigned short*)featb, n4);
    }
    // 2) W transpose+convert
    wtrans_kernel<<<dim3(32, 32, 3), dim3(32, 8), 0, stream>>>(Wq, Wk, Wv, Wbt);
    // 3) QKV projection, BK=64
    gemm_bt<0, 2, 0><<<dim3(M / 128, D / 128, 3), dim3(256), 0, stream>>>(
        featb, Wbt, bqv, bkv, bvv, nullptr, qkv, nullptr, M, D, D, D, D, 1.0f);
    // 4) v -> v^T
    tpose_bf16<<<dim3(D / 32, M / 32), dim3(32, 8), 0, stream>>>(qkv + (size_t)2 * M * D, vbt, M, D);
    // 5) row sums
    hipMemsetAsync(lsum, 0, (size_t)M * 4, stream);

    const float scale = 0.03125f;  // 1/sqrt(1024)
    bf16* qb = qkv;
    bf16* kb = qkv + (size_t)M * D;
    if (C == M) {
        // 6a) full P = exp(q k^T/32): grid 64x64, BK=64
        gemm_bt<1, 2, 0><<<dim3(M / 128, M / 128), dim3(256), 0, stream>>>(
            qb, kb, nullptr, nullptr, nullptr, lsum, Pc, nullptr, M, M, D, D, M, scale);
        // 7a) out = (P v) / lsum, K=8192, BK=64, SWAP grid: P row-slab shared by
        //     consecutive blocks -> P streams once, vbt stays L2-resident
        gemm_bt<3, 2, 1><<<dim3(D / 128, M / 128), dim3(256), 0, stream>>>(
            Pc, vbt, nullptr, nullptr, nullptr, lsum, nullptr, outp, M, D, M, M, D, 0.f);
    } else {
        hipMemsetAsync(outp, 0, (size_t)M * D * 4, stream);
        for (int c = 0; c < M / C; c++) {
            gemm_bt<1, 2, 0><<<dim3(M / 128, C / 128), dim3(256), 0, stream>>>(
                qb, kb + (size_t)c * C * D, nullptr, nullptr, nullptr, lsum, Pc, nullptr,
                M, C, D, D, C, scale);
            gemm_bt<2, 2, 1><<<dim3(D / 128, M / 128), dim3(256), 0, stream>>>(
                Pc, vbt + (size_t)c * C, nullptr, nullptr, nullptr, nullptr, nullptr, outp,
                M, D, C, M, D, 0.f);
        }
        scale_rows<<<dim3(M * D / 4 / 256), dim3(256), 0, stream>>>(outp, lsum);
    }
}

// Round 7
// 449.488 us; speedup vs baseline: 1.9233x; 1.0325x over previous
//
#include <hip/hip_runtime.h>
#include <hip/hip_bf16.h>
#include <stdint.h>

typedef __hip_bfloat16 bf16;
typedef __attribute__((ext_vector_type(8))) short short8;
typedef __attribute__((ext_vector_type(4))) float f32x4;

#define BM 128
#define BN 128

__device__ __forceinline__ unsigned short f2bf_bits(float x) {
    return __builtin_bit_cast(unsigned short, __float2bfloat16(x));
}

// async global->LDS, 16B per lane, LDS dest = wave-uniform base + lane*16
__device__ __forceinline__ void gload_lds16(const bf16* g, bf16* l) {
    __builtin_amdgcn_global_load_lds(
        (const __attribute__((address_space(1))) void*)(const void*)g,
        (__attribute__((address_space(3))) void*)(void*)l,
        16, 0, 0);
}

__global__ void cvt_f32_bf16_x4(const float* __restrict__ in, unsigned short* __restrict__ out, int n4) {
    int i = blockIdx.x * 256 + threadIdx.x;
    if (i < n4) {
        float4 v = reinterpret_cast<const float4*>(in)[i];
        ushort4 o;
        o.x = f2bf_bits(v.x); o.y = f2bf_bits(v.y);
        o.z = f2bf_bits(v.z); o.w = f2bf_bits(v.w);
        reinterpret_cast<ushort4*>(out)[i] = o;
    }
}

// W[z] fp32 [1024][1024] -> Wt bf16 [z][n][k] (transposed)
__global__ void wtrans_kernel(const float* __restrict__ W0, const float* __restrict__ W1,
                              const float* __restrict__ W2, bf16* __restrict__ Wt) {
    __shared__ float tile[32][33];
    const int z = blockIdx.z;
    const float* in = (z == 0) ? W0 : (z == 1) ? W1 : W2;
    bf16* out = Wt + (size_t)z * 1024 * 1024;
    const int bx = blockIdx.x, by = blockIdx.y, tx = threadIdx.x;
    for (int r = threadIdx.y; r < 32; r += 8)
        tile[r][tx] = in[(size_t)(by * 32 + r) * 1024 + bx * 32 + tx];
    __syncthreads();
    for (int r = threadIdx.y; r < 32; r += 8)
        out[(size_t)(bx * 32 + r) * 1024 + by * 32 + tx] = __float2bfloat16(tile[tx][r]);
}

// bf16 transpose: in [rows][cols] -> out [cols][rows]
__global__ void tpose_bf16(const bf16* __restrict__ in, bf16* __restrict__ out, int rows, int cols) {
    __shared__ bf16 tile[32][33];
    const int bx = blockIdx.x, by = blockIdx.y, tx = threadIdx.x;
    for (int r = threadIdx.y; r < 32; r += 8)
        tile[r][tx] = in[(size_t)(by * 32 + r) * cols + bx * 32 + tx];
    __syncthreads();
    for (int r = threadIdx.y; r < 32; r += 8)
        out[(size_t)(bx * 32 + r) * rows + by * 32 + tx] = tile[tx][r];
}

__global__ void scale_rows(float* __restrict__ out, const float* __restrict__ lsum) {
    int i = blockIdx.x * 256 + threadIdx.x;
    float4 v = reinterpret_cast<float4*>(out)[i];
    float inv = 1.0f / lsum[i >> 8];
    v.x *= inv; v.y *= inv; v.z *= inv; v.w *= inv;
    reinterpret_cast<float4*>(out)[i] = v;
}

// C[M][N] = A[M][K] * B[N][K]^T   (A row-stride = K, B row-stride = ldb)
// LDS tiles: KH stacked [128][32] half-tiles (64 B row stride, conflict-free b128).
// SWAP=1: blockIdx.x = N-tiles, blockIdx.y = M-tiles (chunked fallback O).
// SWAP=2: XCD-swizzled O grid (requires gridDim = (8, M/128)): the 8 col-tile
//         blocks sharing one P row-slab map to consecutive slots of ONE XCD
//         (lin%8 round-robin heuristic) -> row-slab fetched once per XCD L2.
// MODE 0: outb = C + bias[col]  (z-slab QKV), LDS-staged coalesced bf16 stores
// MODE 1: outb = exp(C*scale), atomicAdd row-sums -> lsum, LDS-staged stores
// MODE 2: outf += C                      (chunked O fallback)
// MODE 3: outf  = C / lsum[row]          (full-P O path)
template <int MODE, int KH, int SWAP>
__global__ __launch_bounds__(256, 4)
void gemm_bt(const bf16* __restrict__ A, const bf16* __restrict__ B,
             const float* __restrict__ b0, const float* __restrict__ b1,
             const float* __restrict__ b2, float* __restrict__ lsum,
             bf16* __restrict__ outb, float* __restrict__ outf,
             int M, int N, int K, int ldb, int ldout, float scale) {
    constexpr int TILE = 128 * 32;
    constexpr int SELEMS = (2 * KH * TILE < 9216) ? 9216 : 2 * KH * TILE;
    __shared__ bf16 smem[SELEMS];
    bf16* As = smem;             // As + h*TILE
    bf16* Bs = smem + KH * TILE; // Bs + h*TILE

    const int tid  = threadIdx.x;
    const int lane = tid & 63;
    const int wave = tid >> 6;
    const int wm = wave & 1, wn = wave >> 1;
    const int l16  = lane & 15;
    const int quad = lane >> 4;
    long bm0, bn0;
    if (SWAP == 2) {
        const int lin = blockIdx.y * 8 + blockIdx.x;  // x fastest in dispatch order
        const int xcd = lin & 7;
        const int s   = lin >> 3;
        bn0 = (long)(s & 7) * BN;             // col tile 0..7
        bm0 = (long)((s >> 3) * 8 + xcd) * BM; // row tile 0..63, XCD-grouped
    } else {
        bm0 = (long)(SWAP ? blockIdx.y : blockIdx.x) * BM;
        bn0 = (long)(SWAP ? blockIdx.x : blockIdx.y) * BN;
    }

    const float* bias = nullptr;
    if (MODE == 0) {
        const int z = blockIdx.z;
        B    += (size_t)z * N * K;
        outb += (size_t)z * M * ldout;
        bias  = (z == 0) ? b0 : (z == 1) ? b1 : b2;
    }

    // staging: per wave rows [wave*32, wave*32+32); u = 16-row slab, h = K-half.
    const int lrow = lane >> 2;
    const int lcol = (lane & 3) * 8;
    const bf16* gA[2][KH];
    const bf16* gB[2][KH];
    bf16* lA[2][KH];
    bf16* lB[2][KH];
#pragma unroll
    for (int u = 0; u < 2; u++)
#pragma unroll
        for (int h = 0; h < KH; h++) {
            gA[u][h] = A + (size_t)(bm0 + wave * 32 + u * 16 + lrow) * K + h * 32 + lcol;
            gB[u][h] = B + (size_t)(bn0 + wave * 32 + u * 16 + lrow) * ldb + h * 32 + lcol;
            lA[u][h] = As + h * TILE + (wave * 32 + u * 16) * 32;
            lB[u][h] = Bs + h * TILE + (wave * 32 + u * 16) * 32;
        }

    const bf16* Ard = As + (wm * 64 + l16) * 32 + quad * 8;
    const bf16* Brd = Bs + (wn * 64 + l16) * 32 + quad * 8;

    f32x4 acc[4][4];
    const f32x4 zero = {0.f, 0.f, 0.f, 0.f};
#pragma unroll
    for (int i = 0; i < 4; i++)
#pragma unroll
        for (int j = 0; j < 4; j++) acc[i][j] = zero;

    for (int k0 = 0; k0 < K; k0 += KH * 32) {
        __syncthreads();
#pragma unroll
        for (int u = 0; u < 2; u++)
#pragma unroll
            for (int h = 0; h < KH; h++) {
                gload_lds16(gA[u][h] + k0, lA[u][h]);
                gload_lds16(gB[u][h] + k0, lB[u][h]);
            }
        __syncthreads();
#pragma unroll
        for (int h = 0; h < KH; h++) {
            short8 af[4], bfr[4];
#pragma unroll
            for (int mi = 0; mi < 4; mi++)
                af[mi] = *reinterpret_cast<const short8*>(Ard + h * TILE + mi * 16 * 32);
#pragma unroll
            for (int ni = 0; ni < 4; ni++)
                bfr[ni] = *reinterpret_cast<const short8*>(Brd + h * TILE + ni * 16 * 32);
#pragma unroll
            for (int mi = 0; mi < 4; mi++)
#pragma unroll
                for (int ni = 0; ni < 4; ni++)
                    acc[mi][ni] = __builtin_amdgcn_mfma_f32_16x16x32_bf16(af[mi], bfr[ni], acc[mi][ni], 0, 0, 0);
        }
    }

    // C/D layout (m89/m91): col = lane&15, row = quad*4 + r
    if (MODE == 0 || MODE == 1) {
        __syncthreads();  // tiles dead; reuse smem for epilogue staging
        bf16* eb = smem + wave * 1152;  // 16 rows x stride-72 bf16 = 2304 B / wave
        float bcol[4];
        if (MODE == 0) {
#pragma unroll
            for (int ni = 0; ni < 4; ni++) bcol[ni] = bias[bn0 + wn * 64 + l16 + ni * 16];
        }
#pragma unroll
        for (int mi = 0; mi < 4; mi++) {
#pragma unroll
            for (int r = 0; r < 4; r++) {
                float s = 0.f;
#pragma unroll
                for (int ni = 0; ni < 4; ni++) {
                    float v = acc[mi][ni][r];
                    if (MODE == 0) v += bcol[ni];
                    else { v = __expf(v * scale); s += v; }
                    eb[(quad * 4 + r) * 72 + ni * 16 + l16] = __float2bfloat16(v);
                }
                if (MODE == 1) {
                    s += __shfl_xor(s, 1);
                    s += __shfl_xor(s, 2);
                    s += __shfl_xor(s, 4);
                    s += __shfl_xor(s, 8);
                    if (l16 == 0) atomicAdd(&lsum[bm0 + wm * 64 + mi * 16 + quad * 4 + r], s);
                }
            }
            asm volatile("s_waitcnt lgkmcnt(0)" ::: "memory");
#pragma unroll
            for (int p = 0; p < 2; p++) {
                int r2 = p * 8 + (lane >> 3);
                int c2 = (lane & 7) * 8;
                short8 val = *reinterpret_cast<const short8*>(eb + r2 * 72 + c2);
                *reinterpret_cast<short8*>(
                    outb + (size_t)(bm0 + wm * 64 + mi * 16 + r2) * ldout + bn0 + wn * 64 + c2) = val;
            }
            asm volatile("s_waitcnt lgkmcnt(0)" ::: "memory");
        }
    } else {
        const int rb2 = wm * 64 + quad * 4;
        const int cb2 = wn * 64 + l16;
#pragma unroll
        for (int mi = 0; mi < 4; mi++)
#pragma unroll
            for (int r = 0; r < 4; r++) {
                long row = bm0 + rb2 + mi * 16 + r;
                float mul = (MODE == 3) ? 1.0f / lsum[row] : 0.f;
#pragma unroll
                for (int ni = 0; ni < 4; ni++) {
                    long col = bn0 + cb2 + ni * 16;
                    if (MODE == 3) outf[row * ldout + col] = acc[mi][ni][r] * mul;
                    else           outf[row * ldout + col] += acc[mi][ni][r];
                }
            }
    }
}

extern "C" void kernel_launch(void* const* d_in, const int* in_sizes, int n_in,
                              void* d_out, int out_size, void* d_ws, size_t ws_size,
                              hipStream_t stream) {
    const float* feat = (const float*)d_in[0];
    const float* Wq   = (const float*)d_in[1];
    const float* bqv  = (const float*)d_in[2];
    const float* Wk   = (const float*)d_in[3];
    const float* bkv  = (const float*)d_in[4];
    const float* Wv   = (const float*)d_in[5];
    const float* bvv  = (const float*)d_in[6];
    float* outp = (float*)d_out;

    const int M = 8192, D = 1024;
    char* ws = (char*)d_ws;
    size_t off = 0;
    auto carve = [&](size_t bytes) -> char* {
        char* r = ws + off;
        off += (bytes + 255) & ~(size_t)255;
        return r;
    };
    bf16* featb = (bf16*)carve((size_t)M * D * 2);      // dead after QKV gemm
    bf16* Wbt   = (bf16*)carve((size_t)3 * D * D * 2);  // dead after QKV gemm
    bf16* qkv   = (bf16*)carve((size_t)3 * M * D * 2);  // q | k | v slabs
    float* lsum = (float*)carve((size_t)M * 4);
    bf16* vbt   = featb;  // v^T [D][M], aliases dead featb (tpose runs after QKV)
    size_t avail = (ws_size > off) ? ws_size - off : 0;

    int C;  // key-chunk width for P
    if      (avail >= (size_t)M * M * 2)    C = M;     // full P, 128 MB
    else if (avail >= (size_t)M * 4096 * 2) C = 4096;
    else if (avail >= (size_t)M * 2048 * 2) C = 2048;
    else                                    C = 1024;
    bf16* Pc = (bf16*)carve((size_t)M * C * 2);

    // 1) feat -> bf16
    {
        int n4 = M * D / 4;
        cvt_f32_bf16_x4<<<dim3((n4 + 255) / 256), dim3(256), 0, stream>>>(feat, (unsigned short*)featb, n4);
    }
    // 2) W transpose+convert
    wtrans_kernel<<<dim3(32, 32, 3), dim3(32, 8), 0, stream>>>(Wq, Wk, Wv, Wbt);
    // 3) QKV projection, BK=64
    gemm_bt<0, 2, 0><<<dim3(M / 128, D / 128, 3), dim3(256), 0, stream>>>(
        featb, Wbt, bqv, bkv, bvv, nullptr, qkv, nullptr, M, D, D, D, D, 1.0f);
    // 4) v -> v^T
    tpose_bf16<<<dim3(D / 32, M / 32), dim3(32, 8), 0, stream>>>(qkv + (size_t)2 * M * D, vbt, M, D);
    // 5) row sums
    hipMemsetAsync(lsum, 0, (size_t)M * 4, stream);

    const float scale = 0.03125f;  // 1/sqrt(1024)
    bf16* qb = qkv;
    bf16* kb = qkv + (size_t)M * D;
    if (C == M) {
        // 6a) full P = exp(q k^T/32): grid 64x64, BK=64
        gemm_bt<1, 2, 0><<<dim3(M / 128, M / 128), dim3(256), 0, stream>>>(
            qb, kb, nullptr, nullptr, nullptr, lsum, Pc, nullptr, M, M, D, D, M, scale);
        // 7a) out = (P v) / lsum, K=8192, BK=64, XCD-swizzled grid (8 x 64)
        gemm_bt<3, 2, 2><<<dim3(D / 128, M / 128), dim3(256), 0, stream>>>(
            Pc, vbt, nullptr, nullptr, nullptr, lsum, nullptr, outp, M, D, M, M, D, 0.f);
    } else {
        hipMemsetAsync(outp, 0, (size_t)M * D * 4, stream);
        for (int c = 0; c < M / C; c++) {
            gemm_bt<1, 2, 0><<<dim3(M / 128, C / 128), dim3(256), 0, stream>>>(
                qb, kb + (size_t)c * C * D, nullptr, nullptr, nullptr, lsum, Pc, nullptr,
                M, C, D, D, C, scale);
            gemm_bt<2, 2, 1><<<dim3(D / 128, M / 128), dim3(256), 0, stream>>>(
                Pc, vbt + (size_t)c * C, nullptr, nullptr, nullptr, nullptr, nullptr, outp,
                M, D, C, M, D, 0.f);
        }
        scale_rows<<<dim3(M * D / 4 / 256), dim3(256), 0, stream>>>(outp, lsum);
    }
}